// Round 6
// baseline (446.403 us; speedup 1.0000x reference)
//
#include <hip/hip_runtime.h>

// SDPAttention, softmax over the QUERY axis (dim=1), strict causal mask.
// B=16, S=2048, D=128. Inputs fp32, output fp32.
//
// convert: Q,K -> hi/lo bf16 split. vtrans: V -> V^T bf16 (b,d,k).
// pass1: column stats m,l over q>=k. s1 = qh*(kh+kl)  (Qhi staged in LDS,
//        K hi+lo frags in regs). Single-wave blocks, 16 cols each.
// pass2: out = sum_k exp(s2-m[k])/l[k]*V[k]. s2 = (qh+ql)*kh  (Khi staged,
//        Q hi+lo frags in regs). Single-wave blocks, 16 rows each, heavy-first.
// 2048 blocks/pass, ~8 resident/CU -> independent chains/CU, no tail.
// NOTE: __launch_bounds__(64) only — the (64,2) min-waves guarantee in R5
// is the prime suspect for the launch abort (LDS-granule edge at 8 blocks/CU).
//
// ws: m(128K) | l(128K) | Qhi|Qlo|Khi|Klo|Vt (8MB each) = 40.25MB

#define B_ 16
#define S_ 2048
#define D_ 128
#define SCALE 0.08838834764831845f /* 1/sqrt(128) */
#define NEG_BIG -1e30f
#define MCLAMP -1e25f

// Staged hi-only tile row: 128 shorts + 8 pad = 272B = 16*17 (b128-aligned rows)
#define ROWK 136

typedef short bf16x8 __attribute__((ext_vector_type(8)));
typedef float f32x4 __attribute__((ext_vector_type(4)));
typedef unsigned short u16x4 __attribute__((ext_vector_type(4)));

static __device__ __forceinline__ unsigned short f2bf(float f) {
  unsigned int u = __builtin_bit_cast(unsigned int, f);
  u += 0x7FFFu + ((u >> 16) & 1u);  // RNE
  return (unsigned short)(u >> 16);
}
static __device__ __forceinline__ float bf2f(unsigned short h) {
  return __builtin_bit_cast(float, (unsigned int)h << 16);
}

// --------------------------------------------------------------- convert ----
__global__ __launch_bounds__(256) void sdpa_convert(
    const float* __restrict__ Qr, const float* __restrict__ Kr,
    unsigned short* __restrict__ Qhi, unsigned short* __restrict__ Qlo,
    unsigned short* __restrict__ Khi, unsigned short* __restrict__ Klo) {
  const size_t t = (size_t)blockIdx.x * 256 + threadIdx.x;
  const float* src = blockIdx.y ? Kr : Qr;
  unsigned short* hi = blockIdx.y ? Khi : Qhi;
  unsigned short* lo = blockIdx.y ? Klo : Qlo;
  f32x4 x = ((const f32x4*)src)[t];
  u16x4 ho, lv;
#pragma unroll
  for (int j = 0; j < 4; ++j) {
    unsigned short h = f2bf(x[j]);
    ho[j] = h;
    lv[j] = f2bf(x[j] - bf2f(h));
  }
  ((u16x4*)hi)[t] = ho;
  ((u16x4*)lo)[t] = lv;
}

// ---------------------------------------------------------------- vtrans ----
__global__ __launch_bounds__(256) void sdpa_vtrans(
    const float* __restrict__ Vr, unsigned short* __restrict__ Vt) {
  __shared__ unsigned short tile[D_][33];
  const int b = blockIdx.y, k0 = blockIdx.x * 32, tid = threadIdx.x;
#pragma unroll
  for (int it = 0; it < 4; ++it) {
    const int r = it * 8 + (tid >> 5);
    const int c4 = (tid & 31) * 4;
    f32x4 x = *(const f32x4*)(Vr + ((size_t)(b * S_ + k0 + r)) * D_ + c4);
#pragma unroll
    for (int j = 0; j < 4; ++j) tile[c4 + j][r] = f2bf(x[j]);
  }
  __syncthreads();
#pragma unroll
  for (int it = 0; it < 4; ++it) {
    const int d = it * 32 + (tid >> 3);
    const int kq = (tid & 7) * 4;
    u16x4 o = {tile[d][kq], tile[d][kq + 1], tile[d][kq + 2], tile[d][kq + 3]};
    *(u16x4*)(Vt + ((size_t)(b * D_ + d)) * S_ + k0 + kq) = o;
  }
}

// ----------------------------------------------------------------- pass1 ----
// grid (128, B), block 64 (one wave). Wave owns 16 key-columns kt*16..+15.
// K hi+lo frags in regs; Qhi 32-row tiles staged in LDS (double-buffered).
// s1 = qh*kh + qh*kl. MFMA 16x16x32: A[m=l15][k=quad*8+j]; B[k][n=l15];
// C/D reg r -> D[row=quad*4+r][col=l15].
__global__ __launch_bounds__(64) void sdpa_pass1(
    const short* __restrict__ Qhi, const short* __restrict__ Khi,
    const short* __restrict__ Klo, float* __restrict__ m_ws,
    float* __restrict__ l_ws) {
  __shared__ __align__(16) short Qst[2][32 * ROWK];
  const int b = blockIdx.y, kt = blockIdx.x;
  const int lane = threadIdx.x, quad = lane >> 4, l15 = lane & 15;
  const int col = kt * 16 + l15;

  const size_t koff = ((size_t)b * S_ + col) * D_ + quad * 8;
  bf16x8 kh[4], kl[4];
#pragma unroll
  for (int c = 0; c < 4; ++c) {
    kh[c] = *(const bf16x8*)(Khi + koff + c * 32);
    kl[c] = *(const bf16x8*)(Klo + koff + c * 32);
  }

  const int sr = lane >> 1, sh64 = (lane & 1) * 64;  // staging: 64 shorts/lane
  const int q_start = (kt >> 1) * 32;
  const int iters = (S_ - q_start) >> 5;

  {  // prolog: stage tile 0
    const short* sp = Qhi + ((size_t)(b * S_ + q_start + sr)) * D_ + sh64;
    short* dst = &Qst[0][sr * ROWK + sh64];
#pragma unroll
    for (int j = 0; j < 8; ++j) *(bf16x8*)(dst + j * 8) = *(const bf16x8*)(sp + j * 8);
  }
  __syncthreads();

  float m = NEG_BIG, l = 0.f;
  for (int it = 0; it < iters; ++it) {
    const int q0 = q_start + it * 32;
    const int cur = it & 1;
    const bool hasnext = (it + 1 < iters);
    bf16x8 g[8];
    if (hasnext) {  // issue next tile's global loads early
      const short* sp = Qhi + ((size_t)(b * S_ + q0 + 32 + sr)) * D_ + sh64;
#pragma unroll
      for (int j = 0; j < 8; ++j) g[j] = *(const bf16x8*)(sp + j * 8);
    }
    float sv[8];
    float tmax = NEG_BIG;
#pragma unroll
    for (int sub = 0; sub < 2; ++sub) {
      const short* row = &Qst[cur][(sub * 16 + l15) * ROWK + quad * 8];
      f32x4 acc = {0.f, 0.f, 0.f, 0.f};
#pragma unroll
      for (int c = 0; c < 4; ++c) {
        bf16x8 qa = *(const bf16x8*)(row + c * 32);
        acc = __builtin_amdgcn_mfma_f32_16x16x32_bf16(qa, kh[c], acc, 0, 0, 0);
        acc = __builtin_amdgcn_mfma_f32_16x16x32_bf16(qa, kl[c], acc, 0, 0, 0);
      }
#pragma unroll
      for (int r = 0; r < 4; ++r) {
        int q = q0 + sub * 16 + quad * 4 + r;
        float s = acc[r] * SCALE;
        if (q < col) s = NEG_BIG;  // strict causal: k > q masked
        sv[sub * 4 + r] = s;
        tmax = fmaxf(tmax, s);
      }
    }
    tmax = fmaxf(tmax, __shfl_xor(tmax, 16, 64));
    tmax = fmaxf(tmax, __shfl_xor(tmax, 32, 64));
    const float mnew = fmaxf(fmaxf(m, tmax), MCLAMP);
    float tsum = 0.f;
#pragma unroll
    for (int j = 0; j < 8; ++j) tsum += __expf(sv[j] - mnew);
    tsum += __shfl_xor(tsum, 16, 64);
    tsum += __shfl_xor(tsum, 32, 64);
    l = l * __expf(m - mnew) + tsum;
    m = mnew;
    if (hasnext) {
      short* dst = &Qst[1 - cur][sr * ROWK + sh64];
#pragma unroll
      for (int j = 0; j < 8; ++j) *(bf16x8*)(dst + j * 8) = g[j];
    }
    __syncthreads();
  }
  if (quad == 0) {
    m_ws[b * S_ + col] = m;
    l_ws[b * S_ + col] = l;
  }
}

// ----------------------------------------------------------------- pass2 ----
// grid (128, B), block 64 (one wave). Wave owns 16 query-rows, heavy-first.
// Q hi+lo frags in regs; Khi 32-row tiles staged in LDS (double-buffered).
// s2 = qh*kh + ql*kh.
__global__ __launch_bounds__(64) void sdpa_pass2(
    const short* __restrict__ Qhi, const short* __restrict__ Qlo,
    const short* __restrict__ Khi, const unsigned short* __restrict__ Vt,
    const float* __restrict__ m_ws, const float* __restrict__ l_ws,
    float* __restrict__ Out) {
  __shared__ __align__(16) short Kst[2][32 * ROWK];
  __shared__ __align__(16) float Pbuf[16][36];
  const int b = blockIdx.y;
  const int qt = 127 - blockIdx.x;  // heavy blocks dispatch first
  const int lane = threadIdx.x, quad = lane >> 4, l15 = lane & 15;
  const int qrow0 = qt * 16;
  const int rowq = qrow0 + quad * 4;

  const size_t qoff = ((size_t)b * S_ + qrow0 + l15) * D_ + quad * 8;
  bf16x8 qh[4], ql[4];
#pragma unroll
  for (int c = 0; c < 4; ++c) {
    qh[c] = *(const bf16x8*)(Qhi + qoff + c * 32);
    ql[c] = *(const bf16x8*)(Qlo + qoff + c * 32);
  }

  f32x4 acc[8];
#pragma unroll
  for (int dt = 0; dt < 8; ++dt) acc[dt] = (f32x4){0.f, 0.f, 0.f, 0.f};

  const float* mrow = m_ws + b * S_;
  const float* lrow = l_ws + b * S_;
  const int sr = lane >> 1, sh64 = (lane & 1) * 64;
  const int iters = (qt >> 1) + 1;  // k-tiles 0..qt*16+15 in steps of 32

  {  // prolog: stage K tile 0
    const short* sp = Khi + ((size_t)(b * S_ + sr)) * D_ + sh64;
    short* dst = &Kst[0][sr * ROWK + sh64];
#pragma unroll
    for (int j = 0; j < 8; ++j) *(bf16x8*)(dst + j * 8) = *(const bf16x8*)(sp + j * 8);
  }
  __syncthreads();

  for (int it = 0; it < iters; ++it) {
    const int kc = it * 32;
    const int cur = it & 1;
    const bool hasnext = (it + 1 < iters);
    // V^T prefetch for this iteration
    bf16x8 vf[8];
#pragma unroll
    for (int dt = 0; dt < 8; ++dt)
      vf[dt] = *(const bf16x8*)(Vt + ((size_t)b * D_ + dt * 16 + l15) * S_ +
                                kc + quad * 8);
    const float mc0 = mrow[kc + l15], mc1 = mrow[kc + 16 + l15];
    const float rl0 = 1.0f / lrow[kc + l15], rl1 = 1.0f / lrow[kc + 16 + l15];
    // next K tile's global loads
    bf16x8 g[8];
    if (hasnext) {
      const short* sp = Khi + ((size_t)(b * S_ + kc + 32 + sr)) * D_ + sh64;
#pragma unroll
      for (int j = 0; j < 8; ++j) g[j] = *(const bf16x8*)(sp + j * 8);
    }
    // scores from LDS K tile
#pragma unroll
    for (int sub = 0; sub < 2; ++sub) {
      const short* row = &Kst[cur][(sub * 16 + l15) * ROWK + quad * 8];
      f32x4 sa = {0.f, 0.f, 0.f, 0.f};
#pragma unroll
      for (int c = 0; c < 4; ++c) {
        bf16x8 kb = *(const bf16x8*)(row + c * 32);
        sa = __builtin_amdgcn_mfma_f32_16x16x32_bf16(qh[c], kb, sa, 0, 0, 0);
        sa = __builtin_amdgcn_mfma_f32_16x16x32_bf16(ql[c], kb, sa, 0, 0, 0);
      }
      const int colk = kc + sub * 16 + l15;
      const float mc = sub ? mc1 : mc0;
      const float rl = sub ? rl1 : rl0;
#pragma unroll
      for (int r = 0; r < 4; ++r) {
        float p = (colk <= rowq + r) ? __expf(sa[r] * SCALE - mc) * rl : 0.f;
        Pbuf[quad * 4 + r][sub * 16 + l15] = p;  // C-layout -> LDS
      }
    }
    // C-layout (fp32, LDS) -> A-fragment (bf16, regs); wave-private
    const float* pr = &Pbuf[l15][quad * 8];
    f32x4 p0 = *(const f32x4*)(pr);
    f32x4 p1 = *(const f32x4*)(pr + 4);
    bf16x8 pa;
#pragma unroll
    for (int j = 0; j < 4; ++j) {
      pa[j] = (short)f2bf(p0[j]);
      pa[j + 4] = (short)f2bf(p1[j]);
    }
#pragma unroll
    for (int dt = 0; dt < 8; ++dt)
      acc[dt] = __builtin_amdgcn_mfma_f32_16x16x32_bf16(pa, vf[dt], acc[dt],
                                                        0, 0, 0);
    if (hasnext) {
      short* dst = &Kst[1 - cur][sr * ROWK + sh64];
#pragma unroll
      for (int j = 0; j < 8; ++j) *(bf16x8*)(dst + j * 8) = g[j];
    }
    __syncthreads();
  }
  // epilogue: C-layout -> fp32 global
#pragma unroll
  for (int r = 0; r < 4; ++r) {
    float* op = Out + ((size_t)b * S_ + rowq + r) * D_ + l15;
#pragma unroll
    for (int dt = 0; dt < 8; ++dt) op[dt * 16] = acc[dt][r];
  }
}

extern "C" void kernel_launch(void* const* d_in, const int* in_sizes, int n_in,
                              void* d_out, int out_size, void* d_ws, size_t ws_size,
                              hipStream_t stream) {
  char* w = (char*)d_ws;
  float* m_ws = (float*)w;
  float* l_ws = (float*)(w + 131072);
  char* p = w + 262144;
  const size_t TSZ = (size_t)B_ * S_ * D_ * 2;  // 8 MB per bf16 tensor
  unsigned short* Qhi = (unsigned short*)(p);
  unsigned short* Qlo = (unsigned short*)(p + TSZ);
  unsigned short* Khi = (unsigned short*)(p + 2 * TSZ);
  unsigned short* Klo = (unsigned short*)(p + 3 * TSZ);
  unsigned short* Vt  = (unsigned short*)(p + 4 * TSZ);

  sdpa_convert<<<dim3((B_ * S_ * D_ / 4) / 256, 2), 256, 0, stream>>>(
      (const float*)d_in[0], (const float*)d_in[1], Qhi, Qlo, Khi, Klo);
  sdpa_vtrans<<<dim3(S_ / 32, B_), 256, 0, stream>>>((const float*)d_in[2], Vt);
  sdpa_pass1<<<dim3(S_ / 16, B_), 64, 0, stream>>>(
      (const short*)Qhi, (const short*)Khi, (const short*)Klo, m_ws, l_ws);
  sdpa_pass2<<<dim3(S_ / 16, B_), 64, 0, stream>>>(
      (const short*)Qhi, (const short*)Qlo, (const short*)Khi, Vt, m_ws, l_ws,
      (float*)d_out);
}